// Round 9
// baseline (10202.538 us; speedup 1.0000x reference)
//
#include <hip/hip_runtime.h>
#include <math.h>

#define NB 64
#define NT 1024
#define NI 128
#define NH 512
#define NBG 16            // batch-groups of 4 batches
#define BGSTR 3072        // floats per (parity,bg) slice (2688 used + pad)
#define PSTR (NBG * BGSTR)

typedef unsigned long long u64;

// ---------------------------------------------------------------------------
// prep: transpose input-proj weights to k-major [k][j*4+m]; init h data
// (both parities, padded layout) to 1.0f and per-(bg,js) step flags to 0.
// ---------------------------------------------------------------------------
__global__ __launch_bounds__(256) void prep_kernel(
    const float* __restrict__ Wsw, const float* __restrict__ Wsm,
    const float* __restrict__ Wss, const float* __restrict__ Wtcx,
    float* __restrict__ WT_in, float* __restrict__ hdat,
    unsigned* __restrict__ flg)
{
  int idx = blockIdx.x * blockDim.x + threadIdx.x;
  int np  = gridDim.x * blockDim.x;
  for (int i = idx; i < NH * NI; i += np) {
    int j = i >> 7, k = i & 127;            // W is [H][I] row-major
    int o = k * 2048 + j * 4;
    WT_in[o + 0] = Wsw[i];
    WT_in[o + 1] = Wsm[i];
    WT_in[o + 2] = Wss[i];
    WT_in[o + 3] = Wtcx[i];
  }
  for (int i = idx; i < 2 * PSTR; i += np) hdat[i] = 1.0f;  // incl. pads
  for (int i = idx; i < 1024; i += np) flg[i] = 0u;  // [2 par][16 bg][32 js]
}

// ---------------------------------------------------------------------------
// phase1: sensory + tcx for all (b,t).  Block = 32 rows x all 512 j.
// ---------------------------------------------------------------------------
__global__ __launch_bounds__(256, 2) void phase1_kernel(
    const float* __restrict__ x, const float* __restrict__ WT_in,
    const float* __restrict__ bsw, const float* __restrict__ bsm,
    const float* __restrict__ bss, const float* __restrict__ btc,
    float* __restrict__ sens, float* __restrict__ tcx)
{
  __shared__ __align__(16) float xs[32 * NI];   // 16 KB
  const int tid = threadIdx.x;
  const int n0  = blockIdx.x * 32;

  const float4* xsrc = (const float4*)(x + (size_t)n0 * NI);
#pragma unroll
  for (int i = 0; i < 4; i++)
    ((float4*)xs)[i * 256 + tid] = xsrc[i * 256 + tid];
  __syncthreads();

  for (int jj = 0; jj < 2; jj++) {
    const int j = tid + jj * 256;
    float4 acc[32];
#pragma unroll
    for (int n = 0; n < 32; n++) acc[n] = make_float4(0.f, 0.f, 0.f, 0.f);

    const float4* wp = (const float4*)WT_in + j;   // row k at wp[k*512]
#pragma unroll 2
    for (int k = 0; k < NI; k++) {
      float4 w = wp[(size_t)k * 512];
#pragma unroll
      for (int n = 0; n < 32; n++) {
        float xv = xs[n * NI + k];
        acc[n].x = fmaf(xv, w.x, acc[n].x);
        acc[n].y = fmaf(xv, w.y, acc[n].y);
        acc[n].z = fmaf(xv, w.z, acc[n].z);
        acc[n].w = fmaf(xv, w.w, acc[n].w);
      }
    }
    const float b0 = bsw[j], b1 = bsm[j], b2v = bss[j], b3 = btc[j];
#pragma unroll 4
    for (int n = 0; n < 32; n++) {
      float sw = acc[n].x + b0;
      float sm = acc[n].y + b1;
      float ss = acc[n].z + b2v;
      float tc = acc[n].w + b3;
      float sig = 1.f / (1.f + expf(-sm));
      float se  = expf(fminf(ss, 50.f));
      size_t o = (size_t)(n0 + n) * NH + j;
      sens[o] = sw * sig * se;
      tcx[o]  = tc;
    }
  }
}

// ---------------------------------------------------------------------------
// phase2: persistent scan, TWO INTERLEAVED BATCH-CHAINS per block, gathers
// via global_load_lds (zero VGPR in flight — fixes r6's spill).
//
// Ledger: r0/r3/r8 (three different detection protocols) all land 7.3-7.8
// us/step -> the cost is the un-overlapped serial hop chain (publish-drain
// + flag propagate + poll + gather + compute).  Fix: each block serves two
// independent batch-group chains; each half {poll other, ISSUE other's
// gather, compute own} hides the other chain's gather flight under this
// chain's dot.
//
// Geometry: 16 bgs of 4 batches; 256 blocks = 8 pair-cliques x 32 js;
// chains bgA=pc, bgB=pc+8.  Weights depend only on (j,k,gate) -> the two
// chains SHARE wreg (128 VGPRs).  Gather: 3 x global_load_lds dwordx4,
// aux=16 (sc1 = agent-coherent, same path as r8's proven loads).
// Published h layout is padded ((k>>5)*168 + b*36 + (k&31)) so the linear
// LDS copy yields conflict-free ds_read_b128 in the dot (the 4 k-range
// groups of a wave land on bank-quads {0,8,16,24}).
//
// Protocol per chain = r8 verbatim: publish agent stores -> vmcnt(0) ->
// barrier -> flag store; readers lane-poll 32 flags >= t.  Flag t+1 from
// a block implies its gather of h(t) completed (tile barrier precedes its
// compute) -> parity overwrite at t+2 is race-free.  Every half begins
// with a poll whose inherent vmcnt(0) drains that wave's previous-half
// gather before the tile barrier.  Chains use disjoint buffers/flags.
// No XCD-placement assumptions anywhere.
// ---------------------------------------------------------------------------
#define DO_HALF(HLX, BGX, TX, HLY, BGY, TY)                                    \
  {                                                                            \
    { /* poll Y flags (also drains this wave's older VMEM via vmcnt(0)) */     \
      const unsigned wantY = (unsigned)(TY);                                   \
      unsigned* pf = flg + (((TY) & 1) ? 512 : 0) + (BGY) * 32;                \
      for (;;) {                                                               \
        unsigned v = __hip_atomic_load(pf + (ln & 31), __ATOMIC_RELAXED,       \
                                       __HIP_MEMORY_SCOPE_AGENT);              \
        if (__all((int)(v >= wantY))) break;                                   \
        __builtin_amdgcn_s_sleep(1);                                           \
      }                                                                        \
      asm volatile("" ::: "memory");                                           \
    }                                                                          \
    float sens_v = 0.f, tcx_v = 0.f;                                           \
    size_t eidx = 0;                                                           \
    if (tid < 64) {                                                            \
      eidx   = ((size_t)((BGX) * 4 + eb) * NT + (TX)) * NH + ej;               \
      sens_v = out[eidx];                                                      \
      tcx_v  = tcx[eidx];                                                      \
    }                                                                          \
    if ((TY) < NT) { /* issue Y gather: flies hidden under X's compute */      \
      const float* gs = hdat + (((TY) & 1) ? PSTR : 0) + (BGY) * BGSTR;        \
      __builtin_amdgcn_global_load_lds(                                        \
          (const __attribute__((address_space(1))) void*)((const uint4*)gs +   \
                                                          tid),                \
          (__attribute__((address_space(3))) void*)((HLY) + wv * 256), 16, 0,  \
          16);                                                                 \
      __builtin_amdgcn_global_load_lds(                                        \
          (const __attribute__((address_space(1))) void*)((const uint4*)gs +   \
                                                          256 + tid),          \
          (__attribute__((address_space(3))) void*)((HLY) + 1024 + wv * 256),  \
          16, 0, 16);                                                          \
      __builtin_amdgcn_global_load_lds(                                        \
          (const __attribute__((address_space(1))) void*)((const uint4*)gs +   \
                                                          512 + tid),          \
          (__attribute__((address_space(3))) void*)((HLY) + 2048 + wv * 256),  \
          16, 0, 16);                                                          \
    }                                                                          \
    __syncthreads(); /* X1: HLX tile complete across waves */                  \
    float acc[4][4];                                                           \
    _Pragma("unroll") for (int ci = 0; ci < 4; ci++)                           \
        _Pragma("unroll") for (int b2 = 0; b2 < 4; b2++) acc[ci][b2] = 0.f;    \
    {                                                                          \
      const float* hb0 = (HLX) + r * 168;                                      \
      _Pragma("unroll") for (int b2 = 0; b2 < 4; b2++) {                       \
        _Pragma("unroll") for (int c = 0; c < 8; c++) {                        \
          float4 hv = *(const float4*)(hb0 + b2 * 36 + c * 4);                 \
          _Pragma("unroll") for (int ci = 0; ci < 4; ci++) {                   \
            acc[ci][b2] = fmaf(wreg[ci][c * 4 + 0], hv.x, acc[ci][b2]);        \
            acc[ci][b2] = fmaf(wreg[ci][c * 4 + 1], hv.y, acc[ci][b2]);        \
            acc[ci][b2] = fmaf(wreg[ci][c * 4 + 2], hv.z, acc[ci][b2]);        \
            acc[ci][b2] = fmaf(wreg[ci][c * 4 + 3], hv.w, acc[ci][b2]);        \
          }                                                                    \
        }                                                                      \
      }                                                                        \
    }                                                                          \
    _Pragma("unroll") for (int ci = 0; ci < 4; ci++)                           \
        _Pragma("unroll") for (int b2 = 0; b2 < 4; b2++) {                     \
      float v = acc[ci][b2];                                                   \
      v += __shfl_xor(v, 16, 64);                                              \
      v += __shfl_xor(v, 32, 64);                                              \
      acc[ci][b2] = v;                                                         \
    }                                                                          \
    if (ln < 16) {                                                             \
      _Pragma("unroll") for (int ci = 0; ci < 4; ci++)                         \
          _Pragma("unroll") for (int b2 = 0; b2 < 4; b2++)                     \
              red[wv * 272 + ln * 17 + ci * 4 + b2] = acc[ci][b2];             \
    }                                                                          \
    float h_old = 0.f;                                                         \
    if (tid < 64) h_old = (HLX)[eoff];                                         \
    __syncthreads(); /* X2: red visible */                                     \
    if (tid < 64) {                                                            \
      float vals[4];                                                           \
      _Pragma("unroll") for (int g2 = 0; g2 < 4; g2++) {                       \
        int c = ejl * 4 + g2;                                                  \
        int o = (c & 15) * 17 + (c >> 4) * 4 + eb;                             \
        vals[g2] = red[o] + red[272 + o] + red[544 + o] + red[816 + o];        \
      }                                                                        \
      float iwv = vals[0] + bw;                                                \
      float imv = vals[1] + bm;                                                \
      float isv = vals[2] + bs;                                                \
      float z   = tcx_v + vals[3];                                             \
      float tau = fmaxf(z, 0.f) + log1pf(expf(-fabsf(z))) + 0.1f;              \
      float sig = 1.f / (1.f + expf(-imv));                                    \
      float inter = iwv * sig * expf(fminf(isv, 50.f));                        \
      float dh  = (sens_v + inter - h_old) / fmaxf(tau, 1e-8f);                \
      float hnew = h_old + 0.1f * dh;                                          \
      unsigned* dd = (unsigned*)(hdat + ((((TX) + 1) & 1) ? PSTR : 0) +        \
                                 (BGX) * BGSTR);                               \
      __hip_atomic_store(dd + eoff, __float_as_uint(hnew), __ATOMIC_RELAXED,   \
                         __HIP_MEMORY_SCOPE_AGENT);                            \
      out[eidx] = hnew;                                                        \
      asm volatile("s_waitcnt vmcnt(0)" ::: "memory");                         \
    }                                                                          \
    __syncthreads(); /* X3: h stores drained before flag */                    \
    if (tid == 0)                                                              \
      __hip_atomic_store(flg + ((((TX) + 1) & 1) ? 512 : 0) + (BGX) * 32 + js, \
                         (unsigned)((TX) + 1), __ATOMIC_RELAXED,               \
                         __HIP_MEMORY_SCOPE_AGENT);                            \
  }

__global__ __launch_bounds__(256, 1) void phase2_kernel(
    const float* __restrict__ Wiw, const float* __restrict__ Wim,
    const float* __restrict__ Wis, const float* __restrict__ Wtch,
    const float* __restrict__ biw, const float* __restrict__ bim,
    const float* __restrict__ bis,
    const float* __restrict__ tcx, float* __restrict__ out,
    float* __restrict__ hdat, unsigned* __restrict__ flg)
{
  __shared__ __align__(16) float hlA[3072];   // chain-A tile (12 KB, padded)
  __shared__ __align__(16) float hlB[3072];   // chain-B tile (12 KB)
  __shared__ float red[4 * 272];              // reduction scratch

  const int tid = threadIdx.x;
  const int wv  = tid >> 6;
  const int ln  = tid & 63;
  const int pc  = blockIdx.x & 7;     // pair-clique
  const int js  = blockIdx.x >> 3;    // j-slice 0..31
  const int bgA = pc;
  const int bgB = pc + 8;

  const int cg = ln & 15;
  const int r  = wv * 4 + (ln >> 4);  // k-range 0..15
  const int k0 = r << 5;

  // persistent weights (128 VGPRs), SHARED by both chains
  const int g   = cg & 3;
  const int jl0 = cg >> 2;
  const float* Wp = (g == 0) ? Wiw : (g == 1) ? Wim : (g == 2) ? Wis : Wtch;
  float wreg[4][32];
#pragma unroll
  for (int ci = 0; ci < 4; ci++) {
    const float* wrow = Wp + (size_t)(js * 16 + jl0 + 4 * ci) * NH + k0;
#pragma unroll
    for (int kk = 0; kk < 32; kk++) wreg[ci][kk] = wrow[kk];
  }

  // epilogue constants (tid<64 handles (b = tid>>4 in 0..3, jl = tid&15))
  const int ejl = tid & 15;
  const int eb  = tid >> 4;
  const int ej  = js * 16 + ejl;
  const int eoff = ((ej >> 5) * 168) + eb * 36 + (ej & 31);  // padded slot
  float bw = 0.f, bm = 0.f, bs = 0.f;
  if (tid < 64) { bw = biw[ej]; bm = bim[ej]; bs = bis[ej]; }

  // prologue: issue chain-A gather for t=0 (parity 0; prep data ready)
  {
    const float* gs = hdat + bgA * BGSTR;
    __builtin_amdgcn_global_load_lds(
        (const __attribute__((address_space(1))) void*)((const uint4*)gs + tid),
        (__attribute__((address_space(3))) void*)(hlA + wv * 256), 16, 0, 16);
    __builtin_amdgcn_global_load_lds(
        (const __attribute__((address_space(1))) void*)((const uint4*)gs + 256 +
                                                        tid),
        (__attribute__((address_space(3))) void*)(hlA + 1024 + wv * 256), 16, 0,
        16);
    __builtin_amdgcn_global_load_lds(
        (const __attribute__((address_space(1))) void*)((const uint4*)gs + 512 +
                                                        tid),
        (__attribute__((address_space(3))) void*)(hlA + 2048 + wv * 256), 16, 0,
        16);
  }

  for (int t = 0; t < NT; t++) {
    // half A: compute chain A step t; poll+issue chain B step t
    DO_HALF(hlA, bgA, t, hlB, bgB, t);
    // half B: compute chain B step t; poll+issue chain A step t+1
    DO_HALF(hlB, bgB, t, hlA, bgA, t + 1);
  }
}

// ---------------------------------------------------------------------------
extern "C" void kernel_launch(void* const* d_in, const int* in_sizes, int n_in,
                              void* d_out, int out_size, void* d_ws, size_t ws_size,
                              hipStream_t stream) {
  const float* x    = (const float*)d_in[0];
  const float* Wsw  = (const float*)d_in[1];
  const float* bsw  = (const float*)d_in[2];
  const float* Wsm  = (const float*)d_in[3];
  const float* bsm  = (const float*)d_in[4];
  const float* Wss  = (const float*)d_in[5];
  const float* bss  = (const float*)d_in[6];
  const float* Wiw  = (const float*)d_in[7];
  const float* biw  = (const float*)d_in[8];
  const float* Wim  = (const float*)d_in[9];
  const float* bim  = (const float*)d_in[10];
  const float* Wis  = (const float*)d_in[11];
  const float* bis  = (const float*)d_in[12];
  const float* Wtcx = (const float*)d_in[13];
  const float* Wtch = (const float*)d_in[14];
  const float* btc  = (const float*)d_in[15];
  float* out = (float*)d_out;

  // workspace (floats): WT_in[128*2048] | tcx[B*T*H] |
  //                     hdat[2*PSTR f32] | flg[1024 u32]
  float* ws     = (float*)d_ws;
  float* WT_in  = ws;
  float* tcx    = ws + 262144;
  float* hdat   = tcx + (size_t)NB * NT * NH;
  unsigned* flg = (unsigned*)(hdat + 2 * PSTR);

  hipLaunchKernelGGL(prep_kernel, dim3(256), dim3(256), 0, stream,
                     Wsw, Wsm, Wss, Wtcx, WT_in, hdat, flg);

  hipLaunchKernelGGL(phase1_kernel, dim3(NB * NT / 32), dim3(256), 0, stream,
                     x, WT_in, bsw, bsm, bss, btc, out, tcx);

  hipLaunchKernelGGL(phase2_kernel, dim3(256), dim3(256), 0, stream,
                     Wiw, Wim, Wis, Wtch, biw, bim, bis,
                     tcx, out, hdat, flg);
}